// Round 1
// baseline (307.378 us; speedup 1.0000x reference)
//
#include <hip/hip_runtime.h>
#include <cstdint>

typedef __bf16 bf16x8 __attribute__((ext_vector_type(8)));
typedef float f32x4 __attribute__((ext_vector_type(4)));

__device__ __forceinline__ unsigned short f2b(float f) {
    union { float f; uint32_t u; } x; x.f = f;
    uint32_t r = (x.u + 0x7fffu + ((x.u >> 16) & 1u)) >> 16;
    return (unsigned short)r;
}
__device__ __forceinline__ float b2f(unsigned short h) {
    union { float f; uint32_t u; } x; x.u = ((uint32_t)h) << 16;
    return x.f;
}

// ---------------- convert x (fp32 -> bf16), 4 elems/thread ----------------
__global__ __launch_bounds__(256) void convert_x_kernel(const float* __restrict__ x,
                                                        unsigned short* __restrict__ xb) {
    int i = (blockIdx.x * 256 + threadIdx.x) * 4;
    float4 v = *(const float4*)(x + i);
    ushort4 o;
    o.x = f2b(v.x); o.y = f2b(v.y); o.z = f2b(v.z); o.w = f2b(v.w);
    *(ushort4*)(xb + i) = o;
}

// ------------- transpose+convert W[k][n] -> Wt[n][k] (bf16) ---------------
__global__ __launch_bounds__(1024) void transpose_w_kernel(const float* __restrict__ Wq,
                                                           const float* __restrict__ Wk,
                                                           const float* __restrict__ Wv,
                                                           unsigned short* __restrict__ Wt) {
    __shared__ float tile[32][33];
    const float* W = (blockIdx.z == 0) ? Wq : (blockIdx.z == 1) ? Wk : Wv;
    int n0 = blockIdx.x * 32, k0 = blockIdx.y * 32;
    int tx = threadIdx.x, ty = threadIdx.y;
    tile[ty][tx] = W[(k0 + ty) * 1024 + n0 + tx];
    __syncthreads();
    Wt[((long)blockIdx.z * 1024 + n0 + ty) * 1024 + k0 + tx] = f2b(tile[tx][ty]);
}

// ---------------- BT-form bf16 MFMA GEMM: C[m][n] = sum_k A[m][k]*B[n][k] ----------------
// 128x128 block tile, BK=32, 256 threads (4 waves, 2x2 of 64x64), m97 structure.
// EPI 0: QKV projection epilogue (bias, Q scale, V transposed store)
// EPI 1: bf16 store to S (ldc=2048)
// EPI 2: fp32 store to out (ldc=1024)
template <int EPI>
__global__ __launch_bounds__(256) void gemm_bt(const unsigned short* __restrict__ A, int lda, long sA,
                                               const unsigned short* __restrict__ Bm, int ldb, long sB,
                                               void* __restrict__ Cv, long sC, int K,
                                               const float* __restrict__ bq, const float* __restrict__ bk,
                                               const float* __restrict__ bv,
                                               unsigned short* __restrict__ Qb,
                                               unsigned short* __restrict__ Kb,
                                               unsigned short* __restrict__ Vt) {
    __shared__ unsigned short As[128 * 32];
    __shared__ unsigned short Bs[128 * 32];

    const int tid = threadIdx.x;
    const int wave = tid >> 6, lane = tid & 63;
    const int quad = lane >> 4, c16 = lane & 15;
    const int wm = wave >> 1, wn = wave & 1;
    const long bm = (long)blockIdx.y * 128;
    const long bn = (long)blockIdx.x * 128;

    const unsigned short* Ab = A + (long)blockIdx.z * sA;
    const unsigned short* Bb = Bm + (long)blockIdx.z * sB;

    f32x4 acc[4][4];
#pragma unroll
    for (int mi = 0; mi < 4; ++mi)
#pragma unroll
        for (int ni = 0; ni < 4; ++ni)
#pragma unroll
            for (int r = 0; r < 4; ++r) acc[mi][ni][r] = 0.0f;

    // staging: per wave, 2 rounds x 64 lanes x 16B for each of A,B
    const int srow = wave * 16 + (lane >> 2);   // row within 64-row group
    const int skk = (lane & 3) * 8;             // k element offset within row
    const unsigned short* aptr0 = Ab + (bm + srow) * (long)lda + skk;
    const unsigned short* aptr1 = aptr0 + 64L * lda;
    const unsigned short* bptr0 = Bb + (bn + srow) * (long)ldb + skk;
    const unsigned short* bptr1 = bptr0 + 64L * ldb;
    unsigned short* asl0 = &As[(wave * 16) * 32];
    unsigned short* asl1 = &As[(64 + wave * 16) * 32];
    unsigned short* bsl0 = &Bs[(wave * 16) * 32];
    unsigned short* bsl1 = &Bs[(64 + wave * 16) * 32];

    for (int k0 = 0; k0 < K; k0 += 32) {
        __builtin_amdgcn_global_load_lds((const __attribute__((address_space(1))) void*)(aptr0 + k0),
                                         (__attribute__((address_space(3))) void*)asl0, 16, 0, 0);
        __builtin_amdgcn_global_load_lds((const __attribute__((address_space(1))) void*)(aptr1 + k0),
                                         (__attribute__((address_space(3))) void*)asl1, 16, 0, 0);
        __builtin_amdgcn_global_load_lds((const __attribute__((address_space(1))) void*)(bptr0 + k0),
                                         (__attribute__((address_space(3))) void*)bsl0, 16, 0, 0);
        __builtin_amdgcn_global_load_lds((const __attribute__((address_space(1))) void*)(bptr1 + k0),
                                         (__attribute__((address_space(3))) void*)bsl1, 16, 0, 0);
        __syncthreads();

        bf16x8 af[4], bf[4];
#pragma unroll
        for (int mi = 0; mi < 4; ++mi)
            af[mi] = *(const bf16x8*)&As[(wm * 64 + mi * 16 + c16) * 32 + quad * 8];
#pragma unroll
        for (int ni = 0; ni < 4; ++ni)
            bf[ni] = *(const bf16x8*)&Bs[(wn * 64 + ni * 16 + c16) * 32 + quad * 8];
#pragma unroll
        for (int mi = 0; mi < 4; ++mi)
#pragma unroll
            for (int ni = 0; ni < 4; ++ni)
                acc[mi][ni] = __builtin_amdgcn_mfma_f32_16x16x32_bf16(af[mi], bf[ni], acc[mi][ni], 0, 0, 0);
        __syncthreads();
    }

    // epilogue. C/D layout: col = lane&15, row = quad*4 + reg
#pragma unroll
    for (int mi = 0; mi < 4; ++mi) {
        const long row0 = bm + wm * 64 + mi * 16 + quad * 4;
#pragma unroll
        for (int ni = 0; ni < 4; ++ni) {
            const int col = (int)bn + wn * 64 + ni * 16 + c16;
            if constexpr (EPI == 0) {
                if (col < 1024) {
                    const float bias = bq[col];
#pragma unroll
                    for (int r = 0; r < 4; ++r)
                        Qb[(row0 + r) * 1024 + col] = f2b((acc[mi][ni][r] + bias) * 0.03125f);
                } else if (col < 2048) {
                    const float bias = bk[col - 1024];
#pragma unroll
                    for (int r = 0; r < 4; ++r)
                        Kb[(row0 + r) * 1024 + (col - 1024)] = f2b(acc[mi][ni][r] + bias);
                } else {
                    const float bias = bv[col - 2048];
                    const long batch = row0 >> 11;
                    const int n = (int)(row0 & 2047);  // multiple of 4
                    ushort4 o;
                    o.x = f2b(acc[mi][ni][0] + bias);
                    o.y = f2b(acc[mi][ni][1] + bias);
                    o.z = f2b(acc[mi][ni][2] + bias);
                    o.w = f2b(acc[mi][ni][3] + bias);
                    *(ushort4*)&Vt[((batch << 10) + (col - 2048)) * 2048L + n] = o;
                }
            } else if constexpr (EPI == 1) {
                unsigned short* S = (unsigned short*)Cv + (long)blockIdx.z * sC;
#pragma unroll
                for (int r = 0; r < 4; ++r)
                    S[(row0 + r) * 2048 + col] = f2b(acc[mi][ni][r]);
            } else {
                float* O = (float*)Cv + (long)blockIdx.z * sC;
#pragma unroll
                for (int r = 0; r < 4; ++r)
                    O[(row0 + r) * 1024 + col] = acc[mi][ni][r];
            }
        }
    }
}

// ---------------- row softmax over 2048 bf16, in place ----------------
__global__ __launch_bounds__(256) void softmax_kernel(unsigned short* __restrict__ S) {
    const long row = blockIdx.x;
    unsigned short* p = S + row * 2048;
    const int tid = threadIdx.x;
    const int wave = tid >> 6, lane = tid & 63;

    ushort4 u0 = *(const ushort4*)&p[tid * 8];
    ushort4 u1 = *(const ushort4*)&p[tid * 8 + 4];
    float v[8];
    v[0] = b2f(u0.x); v[1] = b2f(u0.y); v[2] = b2f(u0.z); v[3] = b2f(u0.w);
    v[4] = b2f(u1.x); v[5] = b2f(u1.y); v[6] = b2f(u1.z); v[7] = b2f(u1.w);

    float m = v[0];
#pragma unroll
    for (int j = 1; j < 8; ++j) m = fmaxf(m, v[j]);
#pragma unroll
    for (int off = 32; off; off >>= 1) m = fmaxf(m, __shfl_xor(m, off, 64));
    __shared__ float redm[4];
    __shared__ float reds[4];
    if (lane == 0) redm[wave] = m;
    __syncthreads();
    m = fmaxf(fmaxf(redm[0], redm[1]), fmaxf(redm[2], redm[3]));

    float s = 0.0f;
#pragma unroll
    for (int j = 0; j < 8; ++j) { v[j] = __expf(v[j] - m); s += v[j]; }
#pragma unroll
    for (int off = 32; off; off >>= 1) s += __shfl_xor(s, off, 64);
    if (lane == 0) reds[wave] = s;
    __syncthreads();
    s = reds[0] + reds[1] + reds[2] + reds[3];
    const float inv = 1.0f / s;

    u0.x = f2b(v[0] * inv); u0.y = f2b(v[1] * inv); u0.z = f2b(v[2] * inv); u0.w = f2b(v[3] * inv);
    u1.x = f2b(v[4] * inv); u1.y = f2b(v[5] * inv); u1.z = f2b(v[6] * inv); u1.w = f2b(v[7] * inv);
    *(ushort4*)&p[tid * 8] = u0;
    *(ushort4*)&p[tid * 8 + 4] = u1;
}

extern "C" void kernel_launch(void* const* d_in, const int* in_sizes, int n_in,
                              void* d_out, int out_size, void* d_ws, size_t ws_size,
                              hipStream_t stream) {
    const float* x  = (const float*)d_in[0];
    const float* Wq = (const float*)d_in[1];
    const float* Wk = (const float*)d_in[2];
    const float* Wv = (const float*)d_in[3];
    const float* bq = (const float*)d_in[4];
    const float* bk = (const float*)d_in[5];
    const float* bv = (const float*)d_in[6];
    float* out = (float*)d_out;

    char* ws = (char*)d_ws;
    unsigned short* xb = (unsigned short*)ws; ws += 8192L * 1024 * 2;
    unsigned short* Wt = (unsigned short*)ws; ws += 3072L * 1024 * 2;
    unsigned short* Qb = (unsigned short*)ws; ws += 8192L * 1024 * 2;
    unsigned short* Kb = (unsigned short*)ws; ws += 8192L * 1024 * 2;
    unsigned short* Vt = (unsigned short*)ws; ws += 4L * 1024 * 2048 * 2;
    unsigned short* S  = (unsigned short*)ws; ws += 4L * 2048 * 2048 * 2;

    // 1. x -> bf16
    convert_x_kernel<<<8192, 256, 0, stream>>>(x, xb);
    // 2. W -> Wt (bf16, transposed, packed [3072][1024])
    transpose_w_kernel<<<dim3(32, 32, 3), dim3(32, 32), 0, stream>>>(Wq, Wk, Wv, Wt);
    // 3. QKV projection: [8192,3072] = xb @ Wt^T (+bias, Q scaled, V stored transposed)
    gemm_bt<0><<<dim3(24, 64, 1), 256, 0, stream>>>(xb, 1024, 0, Wt, 1024, 0,
                                                    nullptr, 0, 1024, bq, bk, bv, Qb, Kb, Vt);
    // 4. per-batch scores: S[b] = Q[b] @ K[b]^T  (Q pre-scaled by 1/32)
    gemm_bt<1><<<dim3(16, 16, 4), 256, 0, stream>>>(Qb, 1024, 2048L * 1024, Kb, 1024, 2048L * 1024,
                                                    S, 2048L * 2048, 1024,
                                                    nullptr, nullptr, nullptr, nullptr, nullptr, nullptr);
    // 5. softmax rows (in place, bf16)
    softmax_kernel<<<8192, 256, 0, stream>>>(S);
    // 6. out[b] = P[b] @ Vt[b]^T  (fp32 out)
    gemm_bt<2><<<dim3(8, 16, 4), 256, 0, stream>>>(S, 2048, 2048L * 2048, Vt, 2048, 2048L * 1024,
                                                   out, 2048L * 1024, 2048,
                                                   nullptr, nullptr, nullptr, nullptr, nullptr, nullptr);
}

// Round 2
// 279.948 us; speedup vs baseline: 1.0980x; 1.0980x over previous
//
#include <hip/hip_runtime.h>
#include <cstdint>

typedef __bf16 bf16x8 __attribute__((ext_vector_type(8)));
typedef float f32x16 __attribute__((ext_vector_type(16)));

__device__ __forceinline__ unsigned short f2b(float f) {
    union { float f; uint32_t u; } x; x.f = f;
    uint32_t r = (x.u + 0x7fffu + ((x.u >> 16) & 1u)) >> 16;
    return (unsigned short)r;
}
__device__ __forceinline__ float b2f(unsigned short h) {
    union { float f; uint32_t u; } x; x.u = ((uint32_t)h) << 16;
    return x.f;
}

// ---------------- convert x (fp32 -> bf16), 4 elems/thread ----------------
__global__ __launch_bounds__(256) void convert_x_kernel(const float* __restrict__ x,
                                                        unsigned short* __restrict__ xb) {
    int i = (blockIdx.x * 256 + threadIdx.x) * 4;
    float4 v = *(const float4*)(x + i);
    ushort4 o;
    o.x = f2b(v.x); o.y = f2b(v.y); o.z = f2b(v.z); o.w = f2b(v.w);
    *(ushort4*)(xb + i) = o;
}

// ------------- transpose+convert W[k][n] -> Wt[n][k] (bf16) ---------------
__global__ __launch_bounds__(1024) void transpose_w_kernel(const float* __restrict__ Wq,
                                                           const float* __restrict__ Wk,
                                                           const float* __restrict__ Wv,
                                                           unsigned short* __restrict__ Wt) {
    __shared__ float tile[32][33];
    const float* W = (blockIdx.z == 0) ? Wq : (blockIdx.z == 1) ? Wk : Wv;
    int n0 = blockIdx.x * 32, k0 = blockIdx.y * 32;
    int tx = threadIdx.x, ty = threadIdx.y;
    tile[ty][tx] = W[(k0 + ty) * 1024 + n0 + tx];
    __syncthreads();
    Wt[((long)blockIdx.z * 1024 + n0 + ty) * 1024 + k0 + tx] = f2b(tile[tx][ty]);
}

// ---------------- BT-form bf16 MFMA GEMM: C[m][n] = sum_k A[m][k]*B[n][k] ----------------
// 128x128 block tile, BK=64, 256 threads (4 waves, 2x2 of 32x32 wave-tiles via
// v_mfma_f32_32x32x16_bf16). LDS rows hold 64 bf16 (128 B = all 32 banks) with an
// XOR-swizzle on 16B chunks: phys_chunk = log_chunk ^ (row & 7). The swizzle is applied
// at staging time by permuting which global chunk each lane fetches (stays inside the
// same 128B segment -> coalescing unchanged; global_load_lds dest stays lane-linear).
// EPI 0: QKV projection epilogue (bias, Q scale 1/32, V transposed store)
// EPI 1: bf16 store to S (ldc=2048)
// EPI 2: fp32 store to out (ldc=1024)
template <int EPI>
__global__ __launch_bounds__(256) void gemm32(const unsigned short* __restrict__ A, int lda, long sA,
                                              const unsigned short* __restrict__ Bm, int ldb, long sB,
                                              void* __restrict__ Cv, long sC, int K,
                                              const float* __restrict__ bq, const float* __restrict__ bk,
                                              const float* __restrict__ bv,
                                              unsigned short* __restrict__ Qb,
                                              unsigned short* __restrict__ Kb,
                                              unsigned short* __restrict__ Vt) {
    __shared__ unsigned short As[128 * 64];
    __shared__ unsigned short Bs[128 * 64];

    const int tid = threadIdx.x;
    const int wave = tid >> 6, lane = tid & 63;
    const int h = lane >> 5;        // half of wave (k-split / row-split)
    const int l31 = lane & 31;
    const int wm = wave >> 1, wn = wave & 1;
    const long bm = (long)blockIdx.y * 128;
    const long bn = (long)blockIdx.x * 128;

    const unsigned short* Ab = A + (long)blockIdx.z * sA;
    const unsigned short* Bb = Bm + (long)blockIdx.z * sB;

    f32x16 acc[2][2];
#pragma unroll
    for (int mi = 0; mi < 2; ++mi)
#pragma unroll
        for (int ni = 0; ni < 2; ++ni)
#pragma unroll
            for (int r = 0; r < 16; ++r) acc[mi][ni][r] = 0.0f;

    // ---- staging setup: wave stages rows {j*32 + wave*8 + (lane>>3)}, j=0..3
    const int srow_in = lane >> 3;                 // 0..7
    const int cswz = (lane & 7) ^ srow_in;         // swizzled 16B chunk index 0..7
    const unsigned short* aptr[4];
    const unsigned short* bptr[4];
    unsigned short* asl[4];
    unsigned short* bsl[4];
#pragma unroll
    for (int j = 0; j < 4; ++j) {
        const int row = j * 32 + wave * 8 + srow_in;
        aptr[j] = Ab + (bm + row) * (long)lda + cswz * 8;
        bptr[j] = Bb + (bn + row) * (long)ldb + cswz * 8;
        asl[j] = &As[(j * 32 + wave * 8) * 64];
        bsl[j] = &Bs[(j * 32 + wave * 8) * 64];
    }

    // ---- fragment read setup (32x32x16: A row = lane&31, k = (lane>>5)*8 + j)
    const int arow0 = (wm * 64 + l31) * 64;        // + mi*32*64, elems
    const int brow0 = (wn * 64 + l31) * 64;
    int sw[4];
#pragma unroll
    for (int kh = 0; kh < 4; ++kh)
        sw[kh] = (((2 * kh + h) ^ (lane & 7)) * 8);   // swizzled elem offset within row

    for (int k0 = 0; k0 < K; k0 += 64) {
#pragma unroll
        for (int j = 0; j < 4; ++j) {
            __builtin_amdgcn_global_load_lds((const __attribute__((address_space(1))) void*)(aptr[j] + k0),
                                             (__attribute__((address_space(3))) void*)asl[j], 16, 0, 0);
            __builtin_amdgcn_global_load_lds((const __attribute__((address_space(1))) void*)(bptr[j] + k0),
                                             (__attribute__((address_space(3))) void*)bsl[j], 16, 0, 0);
        }
        __syncthreads();

#pragma unroll
        for (int kp = 0; kp < 2; ++kp) {
            bf16x8 af[2][2], bfr[2][2];
#pragma unroll
            for (int mi = 0; mi < 2; ++mi)
#pragma unroll
                for (int kk = 0; kk < 2; ++kk)
                    af[mi][kk] = *(const bf16x8*)&As[arow0 + mi * 32 * 64 + sw[kp * 2 + kk]];
#pragma unroll
            for (int ni = 0; ni < 2; ++ni)
#pragma unroll
                for (int kk = 0; kk < 2; ++kk)
                    bfr[ni][kk] = *(const bf16x8*)&Bs[brow0 + ni * 32 * 64 + sw[kp * 2 + kk]];
#pragma unroll
            for (int kk = 0; kk < 2; ++kk)
#pragma unroll
                for (int mi = 0; mi < 2; ++mi)
#pragma unroll
                    for (int ni = 0; ni < 2; ++ni)
                        acc[mi][ni] = __builtin_amdgcn_mfma_f32_32x32x16_bf16(af[mi][kk], bfr[ni][kk],
                                                                              acc[mi][ni], 0, 0, 0);
        }
        __syncthreads();
    }

    // ---- epilogue. 32x32 C/D layout: col = lane&31, row = (reg&3) + 8*(reg>>2) + 4*(lane>>5)
#pragma unroll
    for (int mi = 0; mi < 2; ++mi) {
#pragma unroll
        for (int ni = 0; ni < 2; ++ni) {
            const f32x16 a = acc[mi][ni];
            const long col = bn + wn * 64 + ni * 32 + l31;
            const long rowB = bm + wm * 64 + mi * 32 + h * 4;
            if constexpr (EPI == 0) {
                if (col < 1024) {
                    const float bias = bq[col];
#pragma unroll
                    for (int g = 0; g < 4; ++g)
#pragma unroll
                        for (int r = 0; r < 4; ++r)
                            Qb[(rowB + g * 8 + r) * 1024 + col] = f2b((a[g * 4 + r] + bias) * 0.03125f);
                } else if (col < 2048) {
                    const float bias = bk[col - 1024];
#pragma unroll
                    for (int g = 0; g < 4; ++g)
#pragma unroll
                        for (int r = 0; r < 4; ++r)
                            Kb[(rowB + g * 8 + r) * 1024 + (col - 1024)] = f2b(a[g * 4 + r] + bias);
                } else {
                    const float bias = bv[col - 2048];
#pragma unroll
                    for (int g = 0; g < 4; ++g) {
                        const long row0 = rowB + g * 8;
                        const long batch = row0 >> 11;
                        const int n = (int)(row0 & 2047);     // multiple of 4
                        ushort4 o;
                        o.x = f2b(a[g * 4 + 0] + bias);
                        o.y = f2b(a[g * 4 + 1] + bias);
                        o.z = f2b(a[g * 4 + 2] + bias);
                        o.w = f2b(a[g * 4 + 3] + bias);
                        *(ushort4*)&Vt[(batch * 1024 + (col - 2048)) * 2048 + n] = o;
                    }
                }
            } else if constexpr (EPI == 1) {
                unsigned short* S = (unsigned short*)Cv + (long)blockIdx.z * sC;
#pragma unroll
                for (int g = 0; g < 4; ++g)
#pragma unroll
                    for (int r = 0; r < 4; ++r)
                        S[(rowB + g * 8 + r) * 2048 + col] = f2b(a[g * 4 + r]);
            } else {
                float* O = (float*)Cv + (long)blockIdx.z * sC;
#pragma unroll
                for (int g = 0; g < 4; ++g)
#pragma unroll
                    for (int r = 0; r < 4; ++r)
                        O[(rowB + g * 8 + r) * 1024 + col] = a[g * 4 + r];
            }
        }
    }
}

// ---------------- row softmax over 2048 bf16, in place ----------------
__global__ __launch_bounds__(256) void softmax_kernel(unsigned short* __restrict__ S) {
    const long row = blockIdx.x;
    unsigned short* p = S + row * 2048;
    const int tid = threadIdx.x;
    const int wave = tid >> 6, lane = tid & 63;

    ushort4 u0 = *(const ushort4*)&p[tid * 8];
    ushort4 u1 = *(const ushort4*)&p[tid * 8 + 4];
    float v[8];
    v[0] = b2f(u0.x); v[1] = b2f(u0.y); v[2] = b2f(u0.z); v[3] = b2f(u0.w);
    v[4] = b2f(u1.x); v[5] = b2f(u1.y); v[6] = b2f(u1.z); v[7] = b2f(u1.w);

    float m = v[0];
#pragma unroll
    for (int j = 1; j < 8; ++j) m = fmaxf(m, v[j]);
#pragma unroll
    for (int off = 32; off; off >>= 1) m = fmaxf(m, __shfl_xor(m, off, 64));
    __shared__ float redm[4];
    __shared__ float reds[4];
    if (lane == 0) redm[wave] = m;
    __syncthreads();
    m = fmaxf(fmaxf(redm[0], redm[1]), fmaxf(redm[2], redm[3]));

    float s = 0.0f;
#pragma unroll
    for (int j = 0; j < 8; ++j) { v[j] = __expf(v[j] - m); s += v[j]; }
#pragma unroll
    for (int off = 32; off; off >>= 1) s += __shfl_xor(s, off, 64);
    if (lane == 0) reds[wave] = s;
    __syncthreads();
    s = reds[0] + reds[1] + reds[2] + reds[3];
    const float inv = 1.0f / s;

    u0.x = f2b(v[0] * inv); u0.y = f2b(v[1] * inv); u0.z = f2b(v[2] * inv); u0.w = f2b(v[3] * inv);
    u1.x = f2b(v[4] * inv); u1.y = f2b(v[5] * inv); u1.z = f2b(v[6] * inv); u1.w = f2b(v[7] * inv);
    *(ushort4*)&p[tid * 8] = u0;
    *(ushort4*)&p[tid * 8 + 4] = u1;
}

extern "C" void kernel_launch(void* const* d_in, const int* in_sizes, int n_in,
                              void* d_out, int out_size, void* d_ws, size_t ws_size,
                              hipStream_t stream) {
    const float* x  = (const float*)d_in[0];
    const float* Wq = (const float*)d_in[1];
    const float* Wk = (const float*)d_in[2];
    const float* Wv = (const float*)d_in[3];
    const float* bq = (const float*)d_in[4];
    const float* bk = (const float*)d_in[5];
    const float* bv = (const float*)d_in[6];
    float* out = (float*)d_out;

    char* ws = (char*)d_ws;
    unsigned short* xb = (unsigned short*)ws; ws += 8192L * 1024 * 2;
    unsigned short* Wt = (unsigned short*)ws; ws += 3072L * 1024 * 2;
    unsigned short* Qb = (unsigned short*)ws; ws += 8192L * 1024 * 2;
    unsigned short* Kb = (unsigned short*)ws; ws += 8192L * 1024 * 2;
    unsigned short* Vt = (unsigned short*)ws; ws += 4L * 1024 * 2048 * 2;
    unsigned short* S  = (unsigned short*)ws; ws += 4L * 2048 * 2048 * 2;

    // 1. x -> bf16
    convert_x_kernel<<<8192, 256, 0, stream>>>(x, xb);
    // 2. W -> Wt (bf16, transposed, packed [3072][1024])
    transpose_w_kernel<<<dim3(32, 32, 3), dim3(32, 32), 0, stream>>>(Wq, Wk, Wv, Wt);
    // 3. QKV projection: [8192,3072] = xb @ Wt^T (+bias, Q scaled, V stored transposed)
    gemm32<0><<<dim3(24, 64, 1), 256, 0, stream>>>(xb, 1024, 0, Wt, 1024, 0,
                                                   nullptr, 0, 1024, bq, bk, bv, Qb, Kb, Vt);
    // 4. per-batch scores: S[b] = Q[b] @ K[b]^T  (Q pre-scaled by 1/32)
    gemm32<1><<<dim3(16, 16, 4), 256, 0, stream>>>(Qb, 1024, 2048L * 1024, Kb, 1024, 2048L * 1024,
                                                   S, 2048L * 2048, 1024,
                                                   nullptr, nullptr, nullptr, nullptr, nullptr, nullptr);
    // 5. softmax rows (in place, bf16)
    softmax_kernel<<<8192, 256, 0, stream>>>(S);
    // 6. out[b] = P[b] @ Vt[b]^T  (fp32 out)
    gemm32<2><<<dim3(8, 16, 4), 256, 0, stream>>>(S, 2048, 2048L * 2048, Vt, 2048, 2048L * 1024,
                                                  out, 2048L * 1024, 2048,
                                                  nullptr, nullptr, nullptr, nullptr, nullptr, nullptr);
}